// Round 2
// baseline (789.080 us; speedup 1.0000x reference)
//
#include <hip/hip_runtime.h>
#include <math.h>

#define D_LEN 2048
#define C_CH  128
#define NB    16

// ---------------------------------------------------------------------------
// Kernel A: three 1x1 convs (yf = Wf x + bf, yg = Wg x + bg, yh = Wh x + bh)
// grid (D/128, B), block 256. LDS: x tile [128][132], W [o][k] stride 132.
// ---------------------------------------------------------------------------
__global__ __launch_bounds__(256) void conv3_kernel(
    const float* __restrict__ x,
    const float* __restrict__ Wf, const float* __restrict__ bf,
    const float* __restrict__ Wg, const float* __restrict__ bg,
    const float* __restrict__ Wh, const float* __restrict__ bh,
    float* __restrict__ yf, float* __restrict__ yg, float* __restrict__ yh)
{
    __shared__ __align__(16) float xs[128 * 132];
    __shared__ __align__(16) float ws[128 * 132];

    const int t    = threadIdx.x;
    const int dblk = blockIdx.x * 128;
    const int b    = blockIdx.y;
    const size_t xbase = (size_t)b * C_CH * D_LEN;

    // load x tile [c][d] 128x128 (float4, coalesced)
    for (int q = t; q < 128 * 32; q += 256) {
        int c  = q >> 5;
        int d4 = (q & 31) * 4;
        float4 v = *(const float4*)(x + xbase + (size_t)c * D_LEN + dblk + d4);
        *(float4*)&xs[c * 132 + d4] = v;
    }

    const int oy = t >> 4, dx = t & 15;
    const int o0 = oy * 8;

    auto do_conv = [&](const float* __restrict__ W, const float* __restrict__ bias,
                       float* __restrict__ Y) {
        __syncthreads();              // previous pass done reading ws
        for (int q = t; q < 128 * 128; q += 256) {
            // q = o*128 + k ; read coalesced, write conflict-free rows
            ws[(q >> 7) * 132 + (q & 127)] = W[q];
        }
        __syncthreads();

        float acc[8][8];
        #pragma unroll
        for (int i = 0; i < 8; ++i)
            #pragma unroll
            for (int j = 0; j < 8; ++j) acc[i][j] = 0.0f;

        for (int k = 0; k < 128; ++k) {
            float4 xa = *(float4*)&xs[k * 132 + dx * 4];
            float4 xb = *(float4*)&xs[k * 132 + 64 + dx * 4];
            float xv[8] = {xa.x, xa.y, xa.z, xa.w, xb.x, xb.y, xb.z, xb.w};
            #pragma unroll
            for (int i = 0; i < 8; ++i) {
                float w = ws[(o0 + i) * 132 + k];
                #pragma unroll
                for (int j = 0; j < 8; ++j) acc[i][j] = fmaf(w, xv[j], acc[i][j]);
            }
        }

        #pragma unroll
        for (int i = 0; i < 8; ++i) {
            float bo = bias[o0 + i];
            float* yr = Y + xbase + (size_t)(o0 + i) * D_LEN + dblk;
            float4 s0 = {acc[i][0] + bo, acc[i][1] + bo, acc[i][2] + bo, acc[i][3] + bo};
            float4 s1 = {acc[i][4] + bo, acc[i][5] + bo, acc[i][6] + bo, acc[i][7] + bo};
            *(float4*)(yr + dx * 4)      = s0;
            *(float4*)(yr + 64 + dx * 4) = s1;
        }
    };

    do_conv(Wf, bf, yf);
    do_conv(Wg, bg, yg);
    do_conv(Wh, bh, yh);
}

// ---------------------------------------------------------------------------
// Kernel B: per-channel BN stats over (B, D) for yf (bid<128) and yg (bid>=128)
// coefA = gamma*rstd ; coefB = beta - mean*coefA
// ---------------------------------------------------------------------------
__global__ __launch_bounds__(256) void bnstats_kernel(
    const float* __restrict__ yf, const float* __restrict__ yg,
    const float* __restrict__ gamma_f, const float* __restrict__ beta_f,
    const float* __restrict__ gamma_g, const float* __restrict__ beta_g,
    float* __restrict__ coefA, float* __restrict__ coefB)
{
    const int bid   = blockIdx.x;      // 0..255
    const int which = bid >> 7;
    const int c     = bid & 127;
    const float* y     = which ? yg : yf;
    const float* gamma = which ? gamma_g : gamma_f;
    const float* beta  = which ? beta_g : beta_f;

    const int t = threadIdx.x;
    float s = 0.0f, ss = 0.0f;
    for (int idx = t; idx < NB * D_LEN; idx += 256) {
        int b = idx >> 11;
        int d = idx & 2047;
        float v = y[((size_t)(b * C_CH + c)) * D_LEN + d];
        s += v;
        ss = fmaf(v, v, ss);
    }
    #pragma unroll
    for (int off = 32; off > 0; off >>= 1) {
        s  += __shfl_down(s, off);
        ss += __shfl_down(ss, off);
    }
    __shared__ float rs[4], rss[4];
    if ((t & 63) == 0) { rs[t >> 6] = s; rss[t >> 6] = ss; }
    __syncthreads();
    if (t == 0) {
        s  = rs[0] + rs[1] + rs[2] + rs[3];
        ss = rss[0] + rss[1] + rss[2] + rss[3];
        const float inv = 1.0f / (float)(NB * D_LEN);
        float m    = s * inv;
        float var  = ss * inv - m * m;
        float rstd = rsqrtf(var + 1e-5f);
        float a    = gamma[c] * rstd;
        coefA[bid] = a;
        coefB[bid] = beta[c] - m * a;
    }
}

// ---------------------------------------------------------------------------
// Kernel C: flash attention. grid (D/64, B), block 256.
// f = relu(af*yf+bf), g = relu(ag*yg+bg) applied at load.
// S[d][e] = scale * sum_c f[c][d] g[c][e]; online softmax over e;
// O[d][c] += P[d][e] h[c][e]; z2[b,c,d] = O[d][c]/l[d].
// ---------------------------------------------------------------------------
#define BQ 64
#define BE 32
#define FS 68
#define GS 36
#define HS 35
#define SS 33

__global__ __launch_bounds__(256) void flashattn_kernel(
    const float* __restrict__ yf, const float* __restrict__ yg,
    const float* __restrict__ yh,
    const float* __restrict__ coefA, const float* __restrict__ coefB,
    float* __restrict__ z2)
{
    __shared__ __align__(16) float fs[128 * FS];
    __shared__ __align__(16) float gs[128 * GS];
    __shared__ __align__(16) float hs[128 * HS];
    __shared__ __align__(16) float Ss[BQ * SS];
    __shared__ float m_arr[BQ], l_arr[BQ], al_arr[BQ];

    const int t    = threadIdx.x;
    const int dblk = blockIdx.x * BQ;
    const int b    = blockIdx.y;
    const size_t base = (size_t)b * C_CH * D_LEN;
    const float scale = 0.0883883476483184f;   // 1/sqrt(128)

    // f tile [c][d] 128 x 64, BN+ReLU fused
    for (int q = t; q < 128 * 16; q += 256) {
        int c  = q >> 4;
        int d4 = (q & 15) * 4;
        float a  = coefA[c];
        float bb = coefB[c];
        float4 v = *(const float4*)(yf + base + (size_t)c * D_LEN + dblk + d4);
        float4 r;
        r.x = fmaxf(fmaf(a, v.x, bb), 0.0f);
        r.y = fmaxf(fmaf(a, v.y, bb), 0.0f);
        r.z = fmaxf(fmaf(a, v.z, bb), 0.0f);
        r.w = fmaxf(fmaf(a, v.w, bb), 0.0f);
        *(float4*)&fs[c * FS + d4] = r;
    }
    if (t < BQ) { m_arr[t] = -1e30f; l_arr[t] = 0.0f; }

    const int dg = t & 15, eg = t >> 4;     // S-phase: d0=4dg, e0=2eg
    const int sr = t >> 2, sq = t & 3;      // softmax: row, quarter
    const int pdg = t & 15, pcg = t >> 4;   // PV: d0=4pdg, c0=8pcg

    float acc2[4][8];
    #pragma unroll
    for (int i = 0; i < 4; ++i)
        #pragma unroll
        for (int j = 0; j < 8; ++j) acc2[i][j] = 0.0f;

    for (int e0blk = 0; e0blk < D_LEN; e0blk += BE) {
        __syncthreads();   // prev PV done with gs/hs (and covers init on iter 0)

        // g (BN+ReLU) and h tiles, 128 x 32 each
        for (int q = t; q < 128 * 8; q += 256) {
            int c  = q >> 3;
            int e4 = (q & 7) * 4;
            float a  = coefA[128 + c];
            float bb = coefB[128 + c];
            float4 v = *(const float4*)(yg + base + (size_t)c * D_LEN + e0blk + e4);
            float4 r;
            r.x = fmaxf(fmaf(a, v.x, bb), 0.0f);
            r.y = fmaxf(fmaf(a, v.y, bb), 0.0f);
            r.z = fmaxf(fmaf(a, v.z, bb), 0.0f);
            r.w = fmaxf(fmaf(a, v.w, bb), 0.0f);
            *(float4*)&gs[c * GS + e4] = r;
            float4 hv = *(const float4*)(yh + base + (size_t)c * D_LEN + e0blk + e4);
            hs[c * HS + e4 + 0] = hv.x;
            hs[c * HS + e4 + 1] = hv.y;
            hs[c * HS + e4 + 2] = hv.z;
            hs[c * HS + e4 + 3] = hv.w;
        }
        __syncthreads();

        // ---- S phase: 4d x 2e per thread -------------------------------
        {
            const int d0 = dg * 4, e0 = eg * 2;
            float s00 = 0, s01 = 0, s10 = 0, s11 = 0, s20 = 0, s21 = 0, s30 = 0, s31 = 0;
            for (int c = 0; c < 128; ++c) {
                float4 f4 = *(float4*)&fs[c * FS + d0];
                float2 g2 = *(float2*)&gs[c * GS + e0];
                s00 = fmaf(f4.x, g2.x, s00); s01 = fmaf(f4.x, g2.y, s01);
                s10 = fmaf(f4.y, g2.x, s10); s11 = fmaf(f4.y, g2.y, s11);
                s20 = fmaf(f4.z, g2.x, s20); s21 = fmaf(f4.z, g2.y, s21);
                s30 = fmaf(f4.w, g2.x, s30); s31 = fmaf(f4.w, g2.y, s31);
            }
            Ss[(d0 + 0) * SS + e0 + 0] = s00 * scale;
            Ss[(d0 + 0) * SS + e0 + 1] = s01 * scale;
            Ss[(d0 + 1) * SS + e0 + 0] = s10 * scale;
            Ss[(d0 + 1) * SS + e0 + 1] = s11 * scale;
            Ss[(d0 + 2) * SS + e0 + 0] = s20 * scale;
            Ss[(d0 + 2) * SS + e0 + 1] = s21 * scale;
            Ss[(d0 + 3) * SS + e0 + 0] = s30 * scale;
            Ss[(d0 + 3) * SS + e0 + 1] = s31 * scale;
        }
        __syncthreads();

        // ---- online softmax: 4 threads per row ------------------------
        {
            float vals[8];
            float mp = -1e30f;
            #pragma unroll
            for (int k = 0; k < 8; ++k) {
                vals[k] = Ss[sr * SS + sq * 8 + k];
                mp = fmaxf(mp, vals[k]);
            }
            mp = fmaxf(mp, __shfl_xor(mp, 1, 4));
            mp = fmaxf(mp, __shfl_xor(mp, 2, 4));
            float mold  = m_arr[sr];
            float mnew  = fmaxf(mold, mp);
            float alpha = __expf(mold - mnew);
            float sump = 0.0f;
            #pragma unroll
            for (int k = 0; k < 8; ++k) {
                float p = __expf(vals[k] - mnew);
                Ss[sr * SS + sq * 8 + k] = p;
                sump += p;
            }
            sump += __shfl_xor(sump, 1, 4);
            sump += __shfl_xor(sump, 2, 4);
            if (sq == 0) {
                m_arr[sr]  = mnew;
                al_arr[sr] = alpha;
                l_arr[sr]  = l_arr[sr] * alpha + sump;
            }
        }
        __syncthreads();

        // ---- PV phase: 4d x 8c per thread -----------------------------
        {
            const int d0 = pdg * 4, c0 = pcg * 8;
            float al0 = al_arr[d0 + 0], al1 = al_arr[d0 + 1];
            float al2 = al_arr[d0 + 2], al3 = al_arr[d0 + 3];
            #pragma unroll
            for (int j = 0; j < 8; ++j) {
                acc2[0][j] *= al0; acc2[1][j] *= al1;
                acc2[2][j] *= al2; acc2[3][j] *= al3;
            }
            for (int e = 0; e < BE; ++e) {
                float p0 = Ss[(d0 + 0) * SS + e];
                float p1 = Ss[(d0 + 1) * SS + e];
                float p2 = Ss[(d0 + 2) * SS + e];
                float p3 = Ss[(d0 + 3) * SS + e];
                #pragma unroll
                for (int j = 0; j < 8; ++j) {
                    float hv = hs[(c0 + j) * HS + e];
                    acc2[0][j] = fmaf(p0, hv, acc2[0][j]);
                    acc2[1][j] = fmaf(p1, hv, acc2[1][j]);
                    acc2[2][j] = fmaf(p2, hv, acc2[2][j]);
                    acc2[3][j] = fmaf(p3, hv, acc2[3][j]);
                }
            }
        }
    }

    // epilogue: z2[b, c, d] = O[d][c] / l[d]   (d-contiguous float4 stores)
    {
        const int d0 = pdg * 4, c0 = pcg * 8;
        float rl0 = 1.0f / l_arr[d0 + 0];
        float rl1 = 1.0f / l_arr[d0 + 1];
        float rl2 = 1.0f / l_arr[d0 + 2];
        float rl3 = 1.0f / l_arr[d0 + 3];
        #pragma unroll
        for (int j = 0; j < 8; ++j) {
            float4 o4 = {acc2[0][j] * rl0, acc2[1][j] * rl1,
                         acc2[2][j] * rl2, acc2[3][j] * rl3};
            *(float4*)(z2 + base + (size_t)(c0 + j) * D_LEN + dblk + d0) = o4;
        }
    }
}

// ---------------------------------------------------------------------------
// Kernel D: out = Wv z2 + bv + x.  grid (D/128, B), block 256.
// ---------------------------------------------------------------------------
__global__ __launch_bounds__(256) void convout_kernel(
    const float* __restrict__ z2, const float* __restrict__ Wv,
    const float* __restrict__ bv, const float* __restrict__ x,
    float* __restrict__ out)
{
    __shared__ __align__(16) float zs[128 * 132];
    __shared__ __align__(16) float ws[128 * 132];

    const int t    = threadIdx.x;
    const int dblk = blockIdx.x * 128;
    const int b    = blockIdx.y;
    const size_t base = (size_t)b * C_CH * D_LEN;

    for (int q = t; q < 128 * 32; q += 256) {
        int c  = q >> 5;
        int d4 = (q & 31) * 4;
        float4 v = *(const float4*)(z2 + base + (size_t)c * D_LEN + dblk + d4);
        *(float4*)&zs[c * 132 + d4] = v;
    }
    for (int q = t; q < 128 * 128; q += 256) {
        ws[(q >> 7) * 132 + (q & 127)] = Wv[q];
    }
    __syncthreads();

    const int oy = t >> 4, dx = t & 15;
    const int o0 = oy * 8;

    float acc[8][8];
    #pragma unroll
    for (int i = 0; i < 8; ++i)
        #pragma unroll
        for (int j = 0; j < 8; ++j) acc[i][j] = 0.0f;

    for (int k = 0; k < 128; ++k) {
        float4 xa = *(float4*)&zs[k * 132 + dx * 4];
        float4 xb = *(float4*)&zs[k * 132 + 64 + dx * 4];
        float xv[8] = {xa.x, xa.y, xa.z, xa.w, xb.x, xb.y, xb.z, xb.w};
        #pragma unroll
        for (int i = 0; i < 8; ++i) {
            float w = ws[(o0 + i) * 132 + k];
            #pragma unroll
            for (int j = 0; j < 8; ++j) acc[i][j] = fmaf(w, xv[j], acc[i][j]);
        }
    }

    #pragma unroll
    for (int i = 0; i < 8; ++i) {
        float bo = bv[o0 + i];
        const float* xr = x + base + (size_t)(o0 + i) * D_LEN + dblk;
        float* orow = out + base + (size_t)(o0 + i) * D_LEN + dblk;
        float4 xv0 = *(const float4*)(xr + dx * 4);
        float4 xv1 = *(const float4*)(xr + 64 + dx * 4);
        float4 s0 = {acc[i][0] + bo + xv0.x, acc[i][1] + bo + xv0.y,
                     acc[i][2] + bo + xv0.z, acc[i][3] + bo + xv0.w};
        float4 s1 = {acc[i][4] + bo + xv1.x, acc[i][5] + bo + xv1.y,
                     acc[i][6] + bo + xv1.z, acc[i][7] + bo + xv1.w};
        *(float4*)(orow + dx * 4)      = s0;
        *(float4*)(orow + 64 + dx * 4) = s1;
    }
}

// ---------------------------------------------------------------------------
extern "C" void kernel_launch(void* const* d_in, const int* in_sizes, int n_in,
                              void* d_out, int out_size, void* d_ws, size_t ws_size,
                              hipStream_t stream)
{
    const float* x   = (const float*)d_in[0];
    const float* Wf  = (const float*)d_in[1];
    const float* bf  = (const float*)d_in[2];
    const float* gf  = (const float*)d_in[3];
    const float* btf = (const float*)d_in[4];
    const float* Wg  = (const float*)d_in[5];
    const float* bg  = (const float*)d_in[6];
    const float* gg  = (const float*)d_in[7];
    const float* btg = (const float*)d_in[8];
    const float* Wh  = (const float*)d_in[9];
    const float* bh  = (const float*)d_in[10];
    const float* Wv  = (const float*)d_in[11];
    const float* bv  = (const float*)d_in[12];
    float* out = (float*)d_out;

    const size_t elems = (size_t)NB * C_CH * D_LEN;   // 4,194,304
    float* yf    = (float*)d_ws;
    float* yg    = yf + elems;
    float* yh    = yg + elems;
    float* z2    = yh + elems;
    float* coefA = z2 + elems;
    float* coefB = coefA + 256;

    conv3_kernel<<<dim3(D_LEN / 128, NB), 256, 0, stream>>>(
        x, Wf, bf, Wg, bg, Wh, bh, yf, yg, yh);
    bnstats_kernel<<<dim3(256), 256, 0, stream>>>(
        yf, yg, gf, btf, gg, btg, coefA, coefB);
    flashattn_kernel<<<dim3(D_LEN / BQ, NB), 256, 0, stream>>>(
        yf, yg, yh, coefA, coefB, z2);
    convout_kernel<<<dim3(D_LEN / 128, NB), 256, 0, stream>>>(
        z2, Wv, bv, x, out);
}

// Round 3
// 268.431 us; speedup vs baseline: 2.9396x; 2.9396x over previous
//
#include <hip/hip_runtime.h>
#include <math.h>

#define D_LEN 2048
#define C_CH  128
#define NB    16

typedef __attribute__((ext_vector_type(8))) short bf16x8;
typedef __attribute__((ext_vector_type(4))) float f32x4;

__device__ __forceinline__ unsigned int f2bf(float x){
    unsigned int u = __float_as_uint(x);
    return (u + 0x7fffu + ((u >> 16) & 1u)) >> 16;     // RNE
}
__device__ __forceinline__ unsigned int pack2(float a, float b){
    return f2bf(a) | (f2bf(b) << 16);
}
__device__ __forceinline__ float bfl(unsigned int u){ return __uint_as_float(u << 16); }
__device__ __forceinline__ float bfh(unsigned int u){ return __uint_as_float(u & 0xffff0000u); }
__device__ __forceinline__ float b2f(short s){
    return __uint_as_float(((unsigned int)(unsigned short)s) << 16);
}

// ---------------------------------------------------------------------------
// Kernel A: three 1x1 convs. f,g stored TRANSPOSED bf16 [b][d][c]; h stored
// original bf16 [b][c][d]. grid (16,16), block 256.
// ---------------------------------------------------------------------------
__global__ __launch_bounds__(256) void conv3_kernel(
    const float* __restrict__ x,
    const float* __restrict__ Wf, const float* __restrict__ bf,
    const float* __restrict__ Wg, const float* __restrict__ bg,
    const float* __restrict__ Wh, const float* __restrict__ bh,
    short* __restrict__ ft, short* __restrict__ gt, short* __restrict__ hh)
{
    __shared__ __align__(16) float xs[128 * 132];
    __shared__ __align__(16) float ws[128 * 132];

    const int t    = threadIdx.x;
    const int dblk = blockIdx.x * 128;
    const int b    = blockIdx.y;
    const size_t xbase = (size_t)b * C_CH * D_LEN;

    for (int q = t; q < 128 * 32; q += 256) {
        int c  = q >> 5;
        int d4 = (q & 31) * 4;
        float4 v = *(const float4*)(x + xbase + (size_t)c * D_LEN + dblk + d4);
        *(float4*)&xs[c * 132 + d4] = v;
    }

    const int oy = t >> 4, dx = t & 15;
    const int o0 = oy * 8;

    auto do_conv = [&](const float* __restrict__ W, const float* __restrict__ bias,
                       short* __restrict__ Y, int transposed) {
        __syncthreads();
        for (int q = t; q < 128 * 128; q += 256)
            ws[(q >> 7) * 132 + (q & 127)] = W[q];
        __syncthreads();

        float acc[8][8];
        #pragma unroll
        for (int i = 0; i < 8; ++i)
            #pragma unroll
            for (int j = 0; j < 8; ++j) acc[i][j] = 0.0f;

        for (int k = 0; k < 128; ++k) {
            float4 xa = *(float4*)&xs[k * 132 + dx * 4];
            float4 xb = *(float4*)&xs[k * 132 + 64 + dx * 4];
            float xv[8] = {xa.x, xa.y, xa.z, xa.w, xb.x, xb.y, xb.z, xb.w};
            #pragma unroll
            for (int i = 0; i < 8; ++i) {
                float w = ws[(o0 + i) * 132 + k];
                #pragma unroll
                for (int j = 0; j < 8; ++j) acc[i][j] = fmaf(w, xv[j], acc[i][j]);
            }
        }

        float bo[8];
        #pragma unroll
        for (int i = 0; i < 8; ++i) bo[i] = bias[o0 + i];

        if (transposed) {
            // Y[b][d][c]: per d-value write 8 contiguous channels (16B)
            #pragma unroll
            for (int j = 0; j < 8; ++j) {
                int d = dblk + dx * 4 + (j & 3) + (j >> 2) * 64;
                uint4 pk;
                pk.x = pack2(acc[0][j] + bo[0], acc[1][j] + bo[1]);
                pk.y = pack2(acc[2][j] + bo[2], acc[3][j] + bo[3]);
                pk.z = pack2(acc[4][j] + bo[4], acc[5][j] + bo[5]);
                pk.w = pack2(acc[6][j] + bo[6], acc[7][j] + bo[7]);
                *(uint4*)&Y[((size_t)b * D_LEN + d) * C_CH + o0] = pk;
            }
        } else {
            // Y[b][c][d]
            #pragma unroll
            for (int i = 0; i < 8; ++i) {
                uint2 w0, w1;
                w0.x = pack2(acc[i][0] + bo[i], acc[i][1] + bo[i]);
                w0.y = pack2(acc[i][2] + bo[i], acc[i][3] + bo[i]);
                w1.x = pack2(acc[i][4] + bo[i], acc[i][5] + bo[i]);
                w1.y = pack2(acc[i][6] + bo[i], acc[i][7] + bo[i]);
                short* row = Y + ((size_t)(b * C_CH) + o0 + i) * D_LEN + dblk + dx * 4;
                *(uint2*)row        = w0;
                *(uint2*)(row + 64) = w1;
            }
        }
    };

    do_conv(Wf, bf, ft, 1);
    do_conv(Wg, bg, gt, 1);
    do_conv(Wh, bh, hh, 0);
}

// ---------------------------------------------------------------------------
// BN stats stage 1: partial per-channel sums over row-chunks of ft/gt.
// grid 128, block 256. part layout: [psF | pssF | psG | pssG], each 128x128.
// ---------------------------------------------------------------------------
__global__ __launch_bounds__(256) void bnstat1_kernel(
    const short* __restrict__ ft, const short* __restrict__ gt,
    float* __restrict__ part)
{
    const int bi = blockIdx.x;
    const int t  = threadIdx.x;
    const int c  = t & 127;
    const int h2 = t >> 7;
    const size_t r0 = (size_t)bi * 256;

    float sf = 0.f, ssf = 0.f, sg = 0.f, ssg = 0.f;
    for (int k = 0; k < 128; ++k) {
        size_t r = r0 + h2 + 2 * (size_t)k;
        float vf = b2f(ft[r * C_CH + c]);
        float vg = b2f(gt[r * C_CH + c]);
        sf += vf; ssf = fmaf(vf, vf, ssf);
        sg += vg; ssg = fmaf(vg, vg, ssg);
    }
    __shared__ float red[4][256];
    red[0][t] = sf; red[1][t] = ssf; red[2][t] = sg; red[3][t] = ssg;
    __syncthreads();
    if (t < 128) {
        part[0 * 16384 + bi * 128 + t] = red[0][t] + red[0][t + 128];
        part[1 * 16384 + bi * 128 + t] = red[1][t] + red[1][t + 128];
        part[2 * 16384 + bi * 128 + t] = red[2][t] + red[2][t + 128];
        part[3 * 16384 + bi * 128 + t] = red[3][t] + red[3][t + 128];
    }
}

// ---------------------------------------------------------------------------
// BN stats stage 2: reduce 128 partials, emit coefA/coefB (f: 0-127, g: 128-255)
// ---------------------------------------------------------------------------
__global__ __launch_bounds__(256) void bnstat2_kernel(
    const float* __restrict__ part,
    const float* __restrict__ gf, const float* __restrict__ btf,
    const float* __restrict__ gg, const float* __restrict__ btg,
    float* __restrict__ coefA, float* __restrict__ coefB)
{
    const int t = threadIdx.x;
    const int which = t >> 7;
    const int c = t & 127;
    const float* ps  = part + which * 32768;
    const float* pss = ps + 16384;
    float s = 0.f, ss = 0.f;
    for (int pb = 0; pb < 128; ++pb) {
        s  += ps[pb * 128 + c];
        ss += pss[pb * 128 + c];
    }
    const float inv = 1.0f / 32768.0f;
    float m    = s * inv;
    float var  = ss * inv - m * m;
    float rstd = rsqrtf(var + 1e-5f);
    float gma  = which ? gg[c] : gf[c];
    float bta  = which ? btg[c] : btf[c];
    float a    = gma * rstd;
    coefA[t] = a;
    coefB[t] = bta - m * a;
}

// ---------------------------------------------------------------------------
// Kernel C: MFMA flash attention. grid (32,16), block 256 (4 waves).
// Wave w owns d-columns w*16..w*16+15 for softmax, c-range w*32..w*32+31 for PV.
// All LDS tiles XOR-swizzled: short_idx ^= (row&7)<<3.
// ---------------------------------------------------------------------------
#define FLASH_BQ 64
#define FLASH_BE 64

__global__ __launch_bounds__(256) void flashattn_kernel(
    const short* __restrict__ ft, const short* __restrict__ gt,
    const short* __restrict__ hh,
    const float* __restrict__ coefA, const float* __restrict__ coefB,
    float* __restrict__ z2)
{
    __shared__ __align__(16) short f_lds[64 * 128];
    __shared__ __align__(16) short g_lds[64 * 128];
    __shared__ __align__(16) short h_lds[128 * 64];
    __shared__ __align__(16) short p_lds[64 * 64];
    __shared__ __align__(16) float alpha_lds[64];
    __shared__ __align__(16) float lsum_lds[64];

    const int t    = threadIdx.x;
    const int lane = t & 63;
    const int w    = t >> 6;
    const int l15  = lane & 15, lg = lane >> 4;
    const int dblk = blockIdx.x * FLASH_BQ;
    const int b    = blockIdx.y;
    const float scale = 0.08838834764831845f;   // 1/sqrt(128)

    // ---- stage f tile [d=64][c=128], BN+ReLU fused ----
    {
        const size_t gb = ((size_t)b * D_LEN + dblk) * C_CH;
        #pragma unroll
        for (int k = 0; k < 4; ++k) {
            int u = t + k * 256;
            int row = u >> 4, cq = u & 15;
            uint4 v = *(const uint4*)(ft + gb + (size_t)row * C_CH + cq * 8);
            const float4 ca0 = *(const float4*)&coefA[cq * 8];
            const float4 ca1 = *(const float4*)&coefA[cq * 8 + 4];
            const float4 cb0 = *(const float4*)&coefB[cq * 8];
            const float4 cb1 = *(const float4*)&coefB[cq * 8 + 4];
            uint4 o;
            o.x = pack2(fmaxf(fmaf(ca0.x, bfl(v.x), cb0.x), 0.f),
                        fmaxf(fmaf(ca0.y, bfh(v.x), cb0.y), 0.f));
            o.y = pack2(fmaxf(fmaf(ca0.z, bfl(v.y), cb0.z), 0.f),
                        fmaxf(fmaf(ca0.w, bfh(v.y), cb0.w), 0.f));
            o.z = pack2(fmaxf(fmaf(ca1.x, bfl(v.z), cb1.x), 0.f),
                        fmaxf(fmaf(ca1.y, bfh(v.z), cb1.y), 0.f));
            o.w = pack2(fmaxf(fmaf(ca1.z, bfl(v.w), cb1.z), 0.f),
                        fmaxf(fmaf(ca1.w, bfh(v.w), cb1.w), 0.f));
            *(uint4*)&f_lds[(row * 128 + cq * 8) ^ ((row & 7) << 3)] = o;
        }
    }

    float m_run = -1e30f, l_run = 0.f;
    const f32x4 fzero = {0.f, 0.f, 0.f, 0.f};
    f32x4 acc[4][2];
    #pragma unroll
    for (int m = 0; m < 4; ++m)
        #pragma unroll
        for (int n = 0; n < 2; ++n) acc[m][n] = fzero;

    __syncthreads();

    // B-fragments of f (loop-invariant): lane holds f[c-contig 8][d = w*16+l15]
    bf16x8 bfrag[4];
    {
        int drow = w * 16 + l15;
        #pragma unroll
        for (int ks = 0; ks < 4; ++ks)
            bfrag[ks] = *(const bf16x8*)&f_lds[(drow * 128 + ks * 32 + lg * 8) ^ ((drow & 7) << 3)];
    }

    for (int e0 = 0; e0 < D_LEN; e0 += FLASH_BE) {
        __syncthreads();   // prev PV done reading h/p; prev QK done reading g

        // ---- stage g tile [e=64][c=128] (BN+ReLU) and h tile [c=128][e=64] ----
        {
            const size_t gb = ((size_t)b * D_LEN + e0) * C_CH;
            #pragma unroll
            for (int k = 0; k < 4; ++k) {
                int u = t + k * 256;
                int row = u >> 4, cq = u & 15;
                uint4 v = *(const uint4*)(gt + gb + (size_t)row * C_CH + cq * 8);
                const float4 ca0 = *(const float4*)&coefA[128 + cq * 8];
                const float4 ca1 = *(const float4*)&coefA[128 + cq * 8 + 4];
                const float4 cb0 = *(const float4*)&coefB[128 + cq * 8];
                const float4 cb1 = *(const float4*)&coefB[128 + cq * 8 + 4];
                uint4 o;
                o.x = pack2(fmaxf(fmaf(ca0.x, bfl(v.x), cb0.x), 0.f),
                            fmaxf(fmaf(ca0.y, bfh(v.x), cb0.y), 0.f));
                o.y = pack2(fmaxf(fmaf(ca0.z, bfl(v.y), cb0.z), 0.f),
                            fmaxf(fmaf(ca0.w, bfh(v.y), cb0.w), 0.f));
                o.z = pack2(fmaxf(fmaf(ca1.x, bfl(v.z), cb1.x), 0.f),
                            fmaxf(fmaf(ca1.y, bfh(v.z), cb1.y), 0.f));
                o.w = pack2(fmaxf(fmaf(ca1.z, bfl(v.w), cb1.z), 0.f),
                            fmaxf(fmaf(ca1.w, bfh(v.w), cb1.w), 0.f));
                *(uint4*)&g_lds[(row * 128 + cq * 8) ^ ((row & 7) << 3)] = o;
            }
            const size_t hb = (size_t)(b * C_CH) * D_LEN + e0;
            #pragma unroll
            for (int k = 0; k < 4; ++k) {
                int u = t + k * 256;
                int row = u >> 3, cq = u & 7;
                uint4 v = *(const uint4*)(hh + hb + (size_t)row * D_LEN + cq * 8);
                *(uint4*)&h_lds[(row * 64 + cq * 8) ^ ((row & 7) << 3)] = v;
            }
        }
        __syncthreads();

        // ---- QK: S^T[e=64][d=16 per wave] via mfma(g, f) ----
        f32x4 st[4];
        #pragma unroll
        for (int m = 0; m < 4; ++m) st[m] = fzero;
        #pragma unroll
        for (int m = 0; m < 4; ++m) {
            int erow = m * 16 + l15;
            #pragma unroll
            for (int ks = 0; ks < 4; ++ks) {
                bf16x8 ag = *(const bf16x8*)&g_lds[(erow * 128 + ks * 32 + lg * 8) ^ ((erow & 7) << 3)];
                st[m] = __builtin_amdgcn_mfma_f32_16x16x32_bf16(ag, bfrag[ks], st[m], 0, 0, 0);
            }
        }

        // ---- online softmax (lane-local over e; d = w*16 + l15) ----
        #pragma unroll
        for (int m = 0; m < 4; ++m) {
            st[m][0] *= scale; st[m][1] *= scale; st[m][2] *= scale; st[m][3] *= scale;
        }
        float mp = -1e30f;
        #pragma unroll
        for (int m = 0; m < 4; ++m)
            #pragma unroll
            for (int r = 0; r < 4; ++r) mp = fmaxf(mp, st[m][r]);
        mp = fmaxf(mp, __shfl_xor(mp, 16));
        mp = fmaxf(mp, __shfl_xor(mp, 32));
        float mnew = fmaxf(m_run, mp);
        float al   = __expf(m_run - mnew);
        m_run = mnew;

        float psum = 0.f;
        const int drow = w * 16 + l15;
        #pragma unroll
        for (int m = 0; m < 4; ++m) {
            float p0 = __expf(st[m][0] - mnew);
            float p1 = __expf(st[m][1] - mnew);
            float p2 = __expf(st[m][2] - mnew);
            float p3 = __expf(st[m][3] - mnew);
            psum += (p0 + p1) + (p2 + p3);
            uint2 pv;
            pv.x = pack2(p0, p1);
            pv.y = pack2(p2, p3);
            *(uint2*)&p_lds[(drow * 64 + m * 16 + lg * 4) ^ ((drow & 7) << 3)] = pv;
        }
        psum += __shfl_xor(psum, 16);
        psum += __shfl_xor(psum, 32);
        l_run = l_run * al + psum;
        if (lane < 16) alpha_lds[w * 16 + lane] = al;
        __syncthreads();

        // ---- rescale + PV: acc[m][n] rows d=m*16+lg*4+r, cols c=w*32+n*16+l15 ----
        #pragma unroll
        for (int m = 0; m < 4; ++m) {
            f32x4 av = *(const f32x4*)&alpha_lds[m * 16 + lg * 4];
            #pragma unroll
            for (int n = 0; n < 2; ++n) {
                acc[m][n][0] *= av[0]; acc[m][n][1] *= av[1];
                acc[m][n][2] *= av[2]; acc[m][n][3] *= av[3];
            }
        }
        #pragma unroll
        for (int ks = 0; ks < 2; ++ks) {
            bf16x8 hbf[2];
            #pragma unroll
            for (int n = 0; n < 2; ++n) {
                int crow = w * 32 + n * 16 + l15;
                hbf[n] = *(const bf16x8*)&h_lds[(crow * 64 + ks * 32 + lg * 8) ^ ((crow & 7) << 3)];
            }
            #pragma unroll
            for (int m = 0; m < 4; ++m) {
                int prow = m * 16 + l15;
                bf16x8 pa = *(const bf16x8*)&p_lds[(prow * 64 + ks * 32 + lg * 8) ^ ((prow & 7) << 3)];
                #pragma unroll
                for (int n = 0; n < 2; ++n)
                    acc[m][n] = __builtin_amdgcn_mfma_f32_16x16x32_bf16(pa, hbf[n], acc[m][n], 0, 0, 0);
            }
        }
    }

    if (lane < 16) lsum_lds[w * 16 + lane] = l_run;
    __syncthreads();

    #pragma unroll
    for (int m = 0; m < 4; ++m) {
        f32x4 lv = *(const f32x4*)&lsum_lds[m * 16 + lg * 4];
        float rl0 = 1.f / lv[0], rl1 = 1.f / lv[1], rl2 = 1.f / lv[2], rl3 = 1.f / lv[3];
        #pragma unroll
        for (int n = 0; n < 2; ++n) {
            int crow = w * 32 + n * 16 + l15;
            float4 o = {acc[m][n][0] * rl0, acc[m][n][1] * rl1,
                        acc[m][n][2] * rl2, acc[m][n][3] * rl3};
            *(float4*)(z2 + ((size_t)(b * C_CH) + crow) * D_LEN + dblk + m * 16 + lg * 4) = o;
        }
    }
}

// ---------------------------------------------------------------------------
// Kernel D: out = Wv z2 + bv + x (fp32). grid (16,16), block 256.
// ---------------------------------------------------------------------------
__global__ __launch_bounds__(256) void convout_kernel(
    const float* __restrict__ z2, const float* __restrict__ Wv,
    const float* __restrict__ bv, const float* __restrict__ x,
    float* __restrict__ out)
{
    __shared__ __align__(16) float zs[128 * 132];
    __shared__ __align__(16) float ws[128 * 132];

    const int t    = threadIdx.x;
    const int dblk = blockIdx.x * 128;
    const int b    = blockIdx.y;
    const size_t base = (size_t)b * C_CH * D_LEN;

    for (int q = t; q < 128 * 32; q += 256) {
        int c  = q >> 5;
        int d4 = (q & 31) * 4;
        float4 v = *(const float4*)(z2 + base + (size_t)c * D_LEN + dblk + d4);
        *(float4*)&zs[c * 132 + d4] = v;
    }
    for (int q = t; q < 128 * 128; q += 256) {
        ws[(q >> 7) * 132 + (q & 127)] = Wv[q];
    }
    __syncthreads();

    const int oy = t >> 4, dx = t & 15;
    const int o0 = oy * 8;

    float acc[8][8];
    #pragma unroll
    for (int i = 0; i < 8; ++i)
        #pragma unroll
        for (int j = 0; j < 8; ++j) acc[i][j] = 0.0f;

    for (int k = 0; k < 128; ++k) {
        float4 xa = *(float4*)&zs[k * 132 + dx * 4];
        float4 xb = *(float4*)&zs[k * 132 + 64 + dx * 4];
        float xv[8] = {xa.x, xa.y, xa.z, xa.w, xb.x, xb.y, xb.z, xb.w};
        #pragma unroll
        for (int i = 0; i < 8; ++i) {
            float w = ws[(o0 + i) * 132 + k];
            #pragma unroll
            for (int j = 0; j < 8; ++j) acc[i][j] = fmaf(w, xv[j], acc[i][j]);
        }
    }

    #pragma unroll
    for (int i = 0; i < 8; ++i) {
        float bo = bv[o0 + i];
        const float* xr = x + base + (size_t)(o0 + i) * D_LEN + dblk;
        float* orow = out + base + (size_t)(o0 + i) * D_LEN + dblk;
        float4 xv0 = *(const float4*)(xr + dx * 4);
        float4 xv1 = *(const float4*)(xr + 64 + dx * 4);
        float4 s0 = {acc[i][0] + bo + xv0.x, acc[i][1] + bo + xv0.y,
                     acc[i][2] + bo + xv0.z, acc[i][3] + bo + xv0.w};
        float4 s1 = {acc[i][4] + bo + xv1.x, acc[i][5] + bo + xv1.y,
                     acc[i][6] + bo + xv1.z, acc[i][7] + bo + xv1.w};
        *(float4*)(orow + dx * 4)      = s0;
        *(float4*)(orow + 64 + dx * 4) = s1;
    }
}

// ---------------------------------------------------------------------------
extern "C" void kernel_launch(void* const* d_in, const int* in_sizes, int n_in,
                              void* d_out, int out_size, void* d_ws, size_t ws_size,
                              hipStream_t stream)
{
    const float* x   = (const float*)d_in[0];
    const float* Wf  = (const float*)d_in[1];
    const float* bf  = (const float*)d_in[2];
    const float* gf  = (const float*)d_in[3];
    const float* btf = (const float*)d_in[4];
    const float* Wg  = (const float*)d_in[5];
    const float* bg  = (const float*)d_in[6];
    const float* gg  = (const float*)d_in[7];
    const float* btg = (const float*)d_in[8];
    const float* Wh  = (const float*)d_in[9];
    const float* bh  = (const float*)d_in[10];
    const float* Wv  = (const float*)d_in[11];
    const float* bv  = (const float*)d_in[12];
    float* out = (float*)d_out;

    const size_t elems = (size_t)NB * C_CH * D_LEN;   // 4,194,304
    short* ft    = (short*)d_ws;
    short* gt    = ft + elems;
    short* hh    = gt + elems;
    float* z2    = (float*)(hh + elems);
    float* part  = z2 + elems;          // 4 * 16384 floats
    float* coefA = part + 65536;
    float* coefB = coefA + 256;

    conv3_kernel<<<dim3(D_LEN / 128, NB), 256, 0, stream>>>(
        x, Wf, bf, Wg, bg, Wh, bh, ft, gt, hh);
    bnstat1_kernel<<<dim3(128), 256, 0, stream>>>(ft, gt, part);
    bnstat2_kernel<<<dim3(1), 256, 0, stream>>>(part, gf, btf, gg, btg, coefA, coefB);
    flashattn_kernel<<<dim3(D_LEN / FLASH_BQ, NB), 256, 0, stream>>>(
        ft, gt, hh, coefA, coefB, z2);
    convout_kernel<<<dim3(D_LEN / 128, NB), 256, 0, stream>>>(
        z2, Wv, bv, x, out);
}

// Round 4
// 208.922 us; speedup vs baseline: 3.7769x; 1.2848x over previous
//
#include <hip/hip_runtime.h>
#include <math.h>

#define D_LEN 2048
#define C_CH  128
#define NB    16

typedef __attribute__((ext_vector_type(8))) short bf16x8;
typedef __attribute__((ext_vector_type(4))) float f32x4;

__device__ __forceinline__ unsigned int f2bf(float x){
    unsigned int u = __float_as_uint(x);
    return (u + 0x7fffu + ((u >> 16) & 1u)) >> 16;     // RNE
}
__device__ __forceinline__ unsigned int pack2(float a, float b){
    return f2bf(a) | (f2bf(b) << 16);
}
__device__ __forceinline__ float bfl(unsigned int u){ return __uint_as_float(u << 16); }
__device__ __forceinline__ float bfh(unsigned int u){ return __uint_as_float(u & 0xffff0000u); }

// ---------------------------------------------------------------------------
// Kernel A: three 1x1 convs via MFMA. grid (32,16) = (d-tile 64, batch).
// ft/gt: raw conv output (no bias; BN cancels it), bf16 [b][d][c].
// hh: conv + bh, bf16 [b][c][d]. Fused per-channel partial stats for f,g.
// LDS: xs fp32 [128][68] (phase1) -> reused as W bf16 [128][128] swizzled;
//      xt bf16 [64][128] swizzled (persistent).
// ---------------------------------------------------------------------------
__global__ __launch_bounds__(256) void conv3_kernel(
    const float* __restrict__ x,
    const float* __restrict__ Wf, const float* __restrict__ Wg,
    const float* __restrict__ Wh, const float* __restrict__ bh,
    short* __restrict__ ft, short* __restrict__ gt, short* __restrict__ hh,
    float* __restrict__ part)
{
    __shared__ __align__(16) char smem[34816 + 16384];
    float* xs = (float*)smem;               // [128][68] fp32
    short* wl = (short*)smem;               // [128][128] bf16, swizzled (after xt)
    short* xt = (short*)(smem + 34816);     // [64][128] bf16, swizzled

    const int t    = threadIdx.x;
    const int lane = t & 63;
    const int w    = t >> 6;
    const int l15  = lane & 15, lg = lane >> 4;
    const int dblk = blockIdx.x * 64;
    const int b    = blockIdx.y;
    const int bid  = b * 32 + blockIdx.x;   // 0..511
    const size_t xbase = (size_t)b * C_CH * D_LEN;

    // phase 1: stage x tile [c=128][d=64] fp32, coalesced
    #pragma unroll
    for (int k = 0; k < 8; ++k) {
        int u = t + k * 256;
        int c = u >> 4, d4 = (u & 15) * 4;
        float4 v = *(const float4*)(x + xbase + (size_t)c * D_LEN + dblk + d4);
        *(float4*)&xs[c * 68 + d4] = v;
    }
    __syncthreads();

    // phase 2: transpose -> xt[d][c] bf16 swizzled
    {
        const int d  = t & 63;
        const int cw = t >> 6;
        #pragma unroll
        for (int k = 0; k < 4; ++k) {
            int c0 = (cw + 4 * k) * 8;
            float v[8];
            #pragma unroll
            for (int j = 0; j < 8; ++j) v[j] = xs[(c0 + j) * 68 + d];
            uint4 o;
            o.x = pack2(v[0], v[1]); o.y = pack2(v[2], v[3]);
            o.z = pack2(v[4], v[5]); o.w = pack2(v[6], v[7]);
            *(uint4*)&xt[d * 128 + (c0 ^ ((d & 7) << 3))] = o;
        }
    }
    __syncthreads();   // xt complete, xs region free

    const f32x4 fzero = {0.f, 0.f, 0.f, 0.f};

    auto do_conv = [&](const float* __restrict__ W, int which) {
        // stage W fp32 -> bf16 swizzled [o][c]
        #pragma unroll
        for (int k = 0; k < 16; ++k) {
            int u = t + k * 256;
            int o = u >> 5, c4 = (u & 31) * 4;
            float4 v = *(const float4*)(W + o * 128 + c4);
            uint2 p;
            p.x = pack2(v.x, v.y);
            p.y = pack2(v.z, v.w);
            *(uint2*)&wl[o * 128 + (c4 ^ ((o & 7) << 3))] = p;
        }
        __syncthreads();

        // hoist A fragments (W rows o)
        bf16x8 af[2][4];
        #pragma unroll
        for (int ot = 0; ot < 2; ++ot) {
            int o = (w * 2 + ot) * 16 + l15;
            #pragma unroll
            for (int ks = 0; ks < 4; ++ks)
                af[ot][ks] = *(const bf16x8*)&wl[o * 128 + ((ks * 32 + lg * 8) ^ ((o & 7) << 3))];
        }

        f32x4 acc[2][4];
        #pragma unroll
        for (int ot = 0; ot < 2; ++ot)
            #pragma unroll
            for (int dg = 0; dg < 4; ++dg) acc[ot][dg] = fzero;

        #pragma unroll
        for (int dg = 0; dg < 4; ++dg) {
            int d = dg * 16 + l15;
            #pragma unroll
            for (int ks = 0; ks < 4; ++ks) {
                bf16x8 bx = *(const bf16x8*)&xt[d * 128 + ((ks * 32 + lg * 8) ^ ((d & 7) << 3))];
                acc[0][dg] = __builtin_amdgcn_mfma_f32_16x16x32_bf16(af[0][ks], bx, acc[0][dg], 0, 0, 0);
                acc[1][dg] = __builtin_amdgcn_mfma_f32_16x16x32_bf16(af[1][ks], bx, acc[1][dg], 0, 0, 0);
            }
        }

        if (which < 2) {
            // fused BN partial stats: per-channel sum / sumsq over this block's 64 d
            float* ps  = part + (size_t)which * 131072;
            float* pss = ps + 65536;
            #pragma unroll
            for (int ot = 0; ot < 2; ++ot) {
                #pragma unroll
                for (int r = 0; r < 4; ++r) {
                    float a0 = acc[ot][0][r], a1 = acc[ot][1][r];
                    float a2 = acc[ot][2][r], a3 = acc[ot][3][r];
                    float s = (a0 + a1) + (a2 + a3);
                    float q = (a0 * a0 + a1 * a1) + (a2 * a2 + a3 * a3);
                    s += __shfl_xor(s, 1); s += __shfl_xor(s, 2);
                    s += __shfl_xor(s, 4); s += __shfl_xor(s, 8);
                    q += __shfl_xor(q, 1); q += __shfl_xor(q, 2);
                    q += __shfl_xor(q, 4); q += __shfl_xor(q, 8);
                    if (l15 == 0) {
                        int o = (w * 2 + ot) * 16 + lg * 4 + r;
                        ps [bid * 128 + o] = s;
                        pss[bid * 128 + o] = q;
                    }
                }
            }
            // store raw conv output, transposed [b][d][c]
            short* Y = which ? gt : ft;
            #pragma unroll
            for (int ot = 0; ot < 2; ++ot) {
                #pragma unroll
                for (int dg = 0; dg < 4; ++dg) {
                    uint2 p;
                    p.x = pack2(acc[ot][dg][0], acc[ot][dg][1]);
                    p.y = pack2(acc[ot][dg][2], acc[ot][dg][3]);
                    *(uint2*)&Y[((size_t)b * D_LEN + dblk + dg * 16 + l15) * C_CH + (w * 2 + ot) * 16 + lg * 4] = p;
                }
            }
        } else {
            // h: + bias, layout [b][c][d]
            #pragma unroll
            for (int ot = 0; ot < 2; ++ot) {
                #pragma unroll
                for (int r = 0; r < 4; ++r) {
                    int o = (w * 2 + ot) * 16 + lg * 4 + r;
                    float bo = bh[o];
                    #pragma unroll
                    for (int dg = 0; dg < 4; ++dg)
                        hh[((size_t)b * C_CH + o) * D_LEN + dblk + dg * 16 + l15] =
                            (short)f2bf(acc[ot][dg][r] + bo);
                }
            }
        }
        __syncthreads();   // done with wl before next conv restages
    };

    do_conv(Wf, 0);
    do_conv(Wg, 1);
    do_conv(Wh, 2);
}

// ---------------------------------------------------------------------------
// BN stats stage 2: reduce 512 partials per channel; fold sqrt(1/sqrt(128))
// into both coefficients (ReLU commutes with positive scale).
// ---------------------------------------------------------------------------
__global__ __launch_bounds__(256) void bnstat2_kernel(
    const float* __restrict__ part,
    const float* __restrict__ gf, const float* __restrict__ btf,
    const float* __restrict__ gg, const float* __restrict__ btg,
    float* __restrict__ coefA, float* __restrict__ coefB)
{
    const int t = threadIdx.x;
    const int which = t >> 7;
    const int c = t & 127;
    const float* ps  = part + (size_t)which * 131072;
    const float* pss = ps + 65536;
    float s = 0.f, q = 0.f;
    for (int pb = 0; pb < 512; ++pb) {
        s += ps [pb * 128 + c];
        q += pss[pb * 128 + c];
    }
    const float inv = 1.0f / 32768.0f;
    const float SQ  = 0.29730177875068026f;   // 128^(-1/4); f*g product carries 1/sqrt(128)
    float m    = s * inv;
    float var  = q * inv - m * m;
    float rstd = rsqrtf(var + 1e-5f);
    float gma  = which ? gg[c] : gf[c];
    float bta  = which ? btg[c] : btf[c];
    float a    = gma * rstd;
    coefA[t] = a * SQ;
    coefB[t] = (bta - m * a) * SQ;
}

// ---------------------------------------------------------------------------
// BN+ReLU apply in place on ft/gt (scale pre-folded). 1 uint4 per thread.
// ---------------------------------------------------------------------------
__global__ __launch_bounds__(256) void bnapply_kernel(
    short* __restrict__ ft, short* __restrict__ gt,
    const float* __restrict__ coefA, const float* __restrict__ coefB)
{
    const int gid   = blockIdx.x * 256 + threadIdx.x;   // 0..1048575
    const int which = gid >> 19;
    const int idx   = gid & 524287;
    short* Y = which ? gt : ft;
    const int c0 = (idx & 15) * 8;
    const float4 a0 = *(const float4*)&coefA[which * 128 + c0];
    const float4 a1 = *(const float4*)&coefA[which * 128 + c0 + 4];
    const float4 b0 = *(const float4*)&coefB[which * 128 + c0];
    const float4 b1 = *(const float4*)&coefB[which * 128 + c0 + 4];
    uint4 v = *(const uint4*)&Y[(size_t)idx * 8];
    uint4 o;
    o.x = pack2(fmaxf(fmaf(a0.x, bfl(v.x), b0.x), 0.f),
                fmaxf(fmaf(a0.y, bfh(v.x), b0.y), 0.f));
    o.y = pack2(fmaxf(fmaf(a0.z, bfl(v.y), b0.z), 0.f),
                fmaxf(fmaf(a0.w, bfh(v.y), b0.w), 0.f));
    o.z = pack2(fmaxf(fmaf(a1.x, bfl(v.z), b1.x), 0.f),
                fmaxf(fmaf(a1.y, bfh(v.z), b1.y), 0.f));
    o.w = pack2(fmaxf(fmaf(a1.z, bfl(v.w), b1.z), 0.f),
                fmaxf(fmaf(a1.w, bfh(v.w), b1.w), 0.f));
    *(uint4*)&Y[(size_t)idx * 8] = o;
}

// ---------------------------------------------------------------------------
// Kernel C: MFMA flash attention (staging = pure copies; scale pre-folded).
// grid (32,16), block 256 (4 waves).
// ---------------------------------------------------------------------------
#define FLASH_BQ 64
#define FLASH_BE 64

__global__ __launch_bounds__(256) void flashattn_kernel(
    const short* __restrict__ ft, const short* __restrict__ gt,
    const short* __restrict__ hh, float* __restrict__ z2)
{
    __shared__ __align__(16) short f_lds[64 * 128];
    __shared__ __align__(16) short g_lds[64 * 128];
    __shared__ __align__(16) short h_lds[128 * 64];
    __shared__ __align__(16) short p_lds[64 * 64];
    __shared__ __align__(16) float alpha_lds[64];
    __shared__ __align__(16) float lsum_lds[64];

    const int t    = threadIdx.x;
    const int lane = t & 63;
    const int w    = t >> 6;
    const int l15  = lane & 15, lg = lane >> 4;
    const int dblk = blockIdx.x * FLASH_BQ;
    const int b    = blockIdx.y;

    // stage f tile [d=64][c=128] (already BN+ReLU+scale applied)
    {
        const size_t gb = ((size_t)b * D_LEN + dblk) * C_CH;
        #pragma unroll
        for (int k = 0; k < 4; ++k) {
            int u = t + k * 256;
            int row = u >> 4, cq = (u & 15) * 8;
            uint4 v = *(const uint4*)(ft + gb + (size_t)row * C_CH + cq);
            *(uint4*)&f_lds[(row * 128 + cq) ^ ((row & 7) << 3)] = v;
        }
    }

    float m_run = -1e30f, l_run = 0.f;
    const f32x4 fzero = {0.f, 0.f, 0.f, 0.f};
    f32x4 acc[4][2];
    #pragma unroll
    for (int m = 0; m < 4; ++m)
        #pragma unroll
        for (int n = 0; n < 2; ++n) acc[m][n] = fzero;

    __syncthreads();

    // hoist loop-invariant B-fragments of f
    bf16x8 bfrag[4];
    {
        int drow = w * 16 + l15;
        #pragma unroll
        for (int ks = 0; ks < 4; ++ks)
            bfrag[ks] = *(const bf16x8*)&f_lds[(drow * 128 + ks * 32 + lg * 8) ^ ((drow & 7) << 3)];
    }

    for (int e0 = 0; e0 < D_LEN; e0 += FLASH_BE) {
        __syncthreads();

        // stage g tile [e=64][c=128] and h tile [c=128][e=64] (pure copies)
        {
            const size_t gb = ((size_t)b * D_LEN + e0) * C_CH;
            #pragma unroll
            for (int k = 0; k < 4; ++k) {
                int u = t + k * 256;
                int row = u >> 4, cq = (u & 15) * 8;
                uint4 v = *(const uint4*)(gt + gb + (size_t)row * C_CH + cq);
                *(uint4*)&g_lds[(row * 128 + cq) ^ ((row & 7) << 3)] = v;
            }
            const size_t hb = (size_t)(b * C_CH) * D_LEN + e0;
            #pragma unroll
            for (int k = 0; k < 4; ++k) {
                int u = t + k * 256;
                int row = u >> 3, e8 = (u & 7) * 8;
                uint4 v = *(const uint4*)(hh + hb + (size_t)row * D_LEN + e8);
                *(uint4*)&h_lds[(row * 64 + e8) ^ ((row & 7) << 3)] = v;
            }
        }
        __syncthreads();

        // QK: S^T[e][d-16-per-wave] via mfma(g, f); scale pre-folded
        f32x4 st[4];
        #pragma unroll
        for (int m = 0; m < 4; ++m) st[m] = fzero;
        #pragma unroll
        for (int m = 0; m < 4; ++m) {
            int erow = m * 16 + l15;
            #pragma unroll
            for (int ks = 0; ks < 4; ++ks) {
                bf16x8 ag = *(const bf16x8*)&g_lds[(erow * 128 + ks * 32 + lg * 8) ^ ((erow & 7) << 3)];
                st[m] = __builtin_amdgcn_mfma_f32_16x16x32_bf16(ag, bfrag[ks], st[m], 0, 0, 0);
            }
        }

        // online softmax (lane-local over e; d = w*16 + l15)
        float mp = -1e30f;
        #pragma unroll
        for (int m = 0; m < 4; ++m)
            #pragma unroll
            for (int r = 0; r < 4; ++r) mp = fmaxf(mp, st[m][r]);
        mp = fmaxf(mp, __shfl_xor(mp, 16));
        mp = fmaxf(mp, __shfl_xor(mp, 32));
        float mnew = fmaxf(m_run, mp);
        float al   = __expf(m_run - mnew);
        m_run = mnew;

        float psum = 0.f;
        const int drow = w * 16 + l15;
        #pragma unroll
        for (int m = 0; m < 4; ++m) {
            float p0 = __expf(st[m][0] - mnew);
            float p1 = __expf(st[m][1] - mnew);
            float p2 = __expf(st[m][2] - mnew);
            float p3 = __expf(st[m][3] - mnew);
            psum += (p0 + p1) + (p2 + p3);
            uint2 pv;
            pv.x = pack2(p0, p1);
            pv.y = pack2(p2, p3);
            *(uint2*)&p_lds[(drow * 64 + m * 16 + lg * 4) ^ ((drow & 7) << 3)] = pv;
        }
        psum += __shfl_xor(psum, 16);
        psum += __shfl_xor(psum, 32);
        l_run = l_run * al + psum;
        if (lane < 16) alpha_lds[w * 16 + lane] = al;
        __syncthreads();

        // rescale + PV
        #pragma unroll
        for (int m = 0; m < 4; ++m) {
            f32x4 av = *(const f32x4*)&alpha_lds[m * 16 + lg * 4];
            #pragma unroll
            for (int n = 0; n < 2; ++n) {
                acc[m][n][0] *= av[0]; acc[m][n][1] *= av[1];
                acc[m][n][2] *= av[2]; acc[m][n][3] *= av[3];
            }
        }
        #pragma unroll
        for (int ks = 0; ks < 2; ++ks) {
            bf16x8 hbf[2];
            #pragma unroll
            for (int n = 0; n < 2; ++n) {
                int crow = w * 32 + n * 16 + l15;
                hbf[n] = *(const bf16x8*)&h_lds[(crow * 64 + ks * 32 + lg * 8) ^ ((crow & 7) << 3)];
            }
            #pragma unroll
            for (int m = 0; m < 4; ++m) {
                int prow = m * 16 + l15;
                bf16x8 pa = *(const bf16x8*)&p_lds[(prow * 64 + ks * 32 + lg * 8) ^ ((prow & 7) << 3)];
                #pragma unroll
                for (int n = 0; n < 2; ++n)
                    acc[m][n] = __builtin_amdgcn_mfma_f32_16x16x32_bf16(pa, hbf[n], acc[m][n], 0, 0, 0);
            }
        }
    }

    if (lane < 16) lsum_lds[w * 16 + lane] = l_run;
    __syncthreads();

    #pragma unroll
    for (int m = 0; m < 4; ++m) {
        f32x4 lv = *(const f32x4*)&lsum_lds[m * 16 + lg * 4];
        float rl0 = 1.f / lv[0], rl1 = 1.f / lv[1], rl2 = 1.f / lv[2], rl3 = 1.f / lv[3];
        #pragma unroll
        for (int n = 0; n < 2; ++n) {
            int crow = w * 32 + n * 16 + l15;
            float4 o = {acc[m][n][0] * rl0, acc[m][n][1] * rl1,
                        acc[m][n][2] * rl2, acc[m][n][3] * rl3};
            *(float4*)(z2 + ((size_t)(b * C_CH) + crow) * D_LEN + dblk + m * 16 + lg * 4) = o;
        }
    }
}

// ---------------------------------------------------------------------------
// Kernel D: out = Wv z2 + bv + x via MFMA. grid (32,16), block 256.
// Same two-phase transpose structure as conv3.
// ---------------------------------------------------------------------------
__global__ __launch_bounds__(256) void convout_kernel(
    const float* __restrict__ z2, const float* __restrict__ Wv,
    const float* __restrict__ bv, const float* __restrict__ x,
    float* __restrict__ out)
{
    __shared__ __align__(16) char smem[34816 + 16384];
    float* zs = (float*)smem;
    short* wl = (short*)smem;
    short* zt = (short*)(smem + 34816);

    const int t    = threadIdx.x;
    const int lane = t & 63;
    const int w    = t >> 6;
    const int l15  = lane & 15, lg = lane >> 4;
    const int dblk = blockIdx.x * 64;
    const int b    = blockIdx.y;
    const size_t base = (size_t)b * C_CH * D_LEN;

    #pragma unroll
    for (int k = 0; k < 8; ++k) {
        int u = t + k * 256;
        int c = u >> 4, d4 = (u & 15) * 4;
        float4 v = *(const float4*)(z2 + base + (size_t)c * D_LEN + dblk + d4);
        *(float4*)&zs[c * 68 + d4] = v;
    }
    __syncthreads();
    {
        const int d  = t & 63;
        const int cw = t >> 6;
        #pragma unroll
        for (int k = 0; k < 4; ++k) {
            int c0 = (cw + 4 * k) * 8;
            float v[8];
            #pragma unroll
            for (int j = 0; j < 8; ++j) v[j] = zs[(c0 + j) * 68 + d];
            uint4 o;
            o.x = pack2(v[0], v[1]); o.y = pack2(v[2], v[3]);
            o.z = pack2(v[4], v[5]); o.w = pack2(v[6], v[7]);
            *(uint4*)&zt[d * 128 + (c0 ^ ((d & 7) << 3))] = o;
        }
    }
    __syncthreads();
    #pragma unroll
    for (int k = 0; k < 16; ++k) {
        int u = t + k * 256;
        int o = u >> 5, c4 = (u & 31) * 4;
        float4 v = *(const float4*)(Wv + o * 128 + c4);
        uint2 p;
        p.x = pack2(v.x, v.y);
        p.y = pack2(v.z, v.w);
        *(uint2*)&wl[o * 128 + (c4 ^ ((o & 7) << 3))] = p;
    }
    __syncthreads();

    bf16x8 af[2][4];
    #pragma unroll
    for (int ot = 0; ot < 2; ++ot) {
        int o = (w * 2 + ot) * 16 + l15;
        #pragma unroll
        for (int ks = 0; ks < 4; ++ks)
            af[ot][ks] = *(const bf16x8*)&wl[o * 128 + ((ks * 32 + lg * 8) ^ ((o & 7) << 3))];
    }

    const f32x4 fzero = {0.f, 0.f, 0.f, 0.f};
    f32x4 acc[2][4];
    #pragma unroll
    for (int ot = 0; ot < 2; ++ot)
        #pragma unroll
        for (int dg = 0; dg < 4; ++dg) acc[ot][dg] = fzero;

    #pragma unroll
    for (int dg = 0; dg < 4; ++dg) {
        int d = dg * 16 + l15;
        #pragma unroll
        for (int ks = 0; ks < 4; ++ks) {
            bf16x8 bx = *(const bf16x8*)&zt[d * 128 + ((ks * 32 + lg * 8) ^ ((d & 7) << 3))];
            acc[0][dg] = __builtin_amdgcn_mfma_f32_16x16x32_bf16(af[0][ks], bx, acc[0][dg], 0, 0, 0);
            acc[1][dg] = __builtin_amdgcn_mfma_f32_16x16x32_bf16(af[1][ks], bx, acc[1][dg], 0, 0, 0);
        }
    }

    #pragma unroll
    for (int ot = 0; ot < 2; ++ot) {
        #pragma unroll
        for (int r = 0; r < 4; ++r) {
            int o = (w * 2 + ot) * 16 + lg * 4 + r;
            float bo = bv[o];
            const float* xr  = x   + base + (size_t)o * D_LEN + dblk;
            float*      orow = out + base + (size_t)o * D_LEN + dblk;
            #pragma unroll
            for (int dg = 0; dg < 4; ++dg) {
                int d = dg * 16 + l15;
                orow[d] = acc[ot][dg][r] + bo + xr[d];
            }
        }
    }
}

// ---------------------------------------------------------------------------
extern "C" void kernel_launch(void* const* d_in, const int* in_sizes, int n_in,
                              void* d_out, int out_size, void* d_ws, size_t ws_size,
                              hipStream_t stream)
{
    const float* x   = (const float*)d_in[0];
    const float* Wf  = (const float*)d_in[1];
    const float* gf  = (const float*)d_in[3];
    const float* btf = (const float*)d_in[4];
    const float* Wg  = (const float*)d_in[5];
    const float* gg  = (const float*)d_in[7];
    const float* btg = (const float*)d_in[8];
    const float* Wh  = (const float*)d_in[9];
    const float* bh  = (const float*)d_in[10];
    const float* Wv  = (const float*)d_in[11];
    const float* bv  = (const float*)d_in[12];
    float* out = (float*)d_out;

    const size_t elems = (size_t)NB * C_CH * D_LEN;   // 4,194,304
    short* ft    = (short*)d_ws;
    short* gt    = ft + elems;
    short* hh    = gt + elems;
    float* z2    = (float*)(hh + elems);
    float* part  = z2 + elems;            // 4 * 65536 floats
    float* coefA = part + 262144;
    float* coefB = coefA + 256;

    conv3_kernel<<<dim3(32, NB), 256, 0, stream>>>(
        x, Wf, Wg, Wh, bh, ft, gt, hh, part);
    bnstat2_kernel<<<dim3(1), 256, 0, stream>>>(
        part, gf, btf, gg, btg, coefA, coefB);
    bnapply_kernel<<<dim3(4096), 256, 0, stream>>>(ft, gt, coefA, coefB);
    flashattn_kernel<<<dim3(D_LEN / FLASH_BQ, NB), 256, 0, stream>>>(
        ft, gt, hh, z2);
    convout_kernel<<<dim3(32, NB), 256, 0, stream>>>(
        z2, Wv, bv, x, out);
}